// Round 9
// baseline (228.068 us; speedup 1.0000x reference)
//
#include <hip/hip_runtime.h>
#include <hip/hip_bf16.h>
#include <hip/hip_fp16.h>

#define BB 16
#define LL 2048
#define DD 128
#define SCALE 0.08838834764831845f
#define CEXP 12.0f
#define NT 32        // k-tiles of 64

typedef _Float16 f16x8 __attribute__((ext_vector_type(8)));
typedef float f32x16 __attribute__((ext_vector_type(16)));

#define MFMA32(a,b,c) __builtin_amdgcn_mfma_f32_32x32x16_f16((a),(b),(c),0,0,0)

// LDS map (main): KB 2x16K | VB 2x16K | PB 8K | RED 512B  => 74240 B => 2 WGs/CU
#define OFF_KB   0
#define OFF_VB   32768
#define OFF_PB   65536
#define OFF_RED  73728
#define LDS_MAIN 74240

#define WAITVM(N)  asm volatile("s_waitcnt vmcnt(" #N ")" ::: "memory")
#define MEMFENCE   asm volatile("" ::: "memory")
#define SB0        __builtin_amdgcn_sched_barrier(0)

__device__ __forceinline__ f16x8 as_f16x8(uint4 v){
  union { uint4 u; f16x8 h; } x; x.u = v; return x.h;
}
__device__ __forceinline__ unsigned pkf16(float a, float b){
  __half ha = __float2half_rn(a), hb = __float2half_rn(b);
  return (unsigned)__half_as_ushort(ha) | ((unsigned)__half_as_ushort(hb) << 16);
}
__device__ __forceinline__ unsigned pkrtz(float a, float b){
  union { decltype(__builtin_amdgcn_cvt_pkrtz(0.f, 0.f)) h; unsigned u; } x;
  x.h = __builtin_amdgcn_cvt_pkrtz(a, b);
  return x.u;
}
__device__ __forceinline__ void stage16(const unsigned char* g, char* l){
  __builtin_amdgcn_global_load_lds(
      (const __attribute__((address_space(1))) void*)g,
      (__attribute__((address_space(3))) void*)l, 16, 0, 0);
}
__device__ __forceinline__ void stage2(const unsigned char* g, char* l, int soff){
  stage16(g + soff, l + soff);
  stage16(g + soff + 1024, l + soff + 1024);
}

// ---------- prep: mask->bits | K -> fp16 swizzled k-major image | V -> fp16 swizzled d-major ----------
__global__ __launch_bounds__(256) void prep_all(
    const float* __restrict__ K, const float* __restrict__ V,
    const int* __restrict__ M,
    unsigned char* __restrict__ kimg, unsigned char* __restrict__ vimg,
    unsigned int* __restrict__ bm)
{
  __shared__ float t[32][65];
  const int bid = blockIdx.x, tid = threadIdx.x;
  if (bid < 8192) {
    const size_t wi = (size_t)bid * 256 + tid;
    const int* mp = M + wi * 32;
    unsigned int wrd = 0;
#pragma unroll
    for (int j = 0; j < 8; ++j) {
      int4 v = *(const int4*)(mp + j*4);
      wrd |= (v.x ? 1u : 0u) << (4*j)
          |  (v.y ? 1u : 0u) << (4*j+1)
          |  (v.z ? 1u : 0u) << (4*j+2)
          |  (v.w ? 1u : 0u) << (4*j+3);
    }
    bm[wi] = wrd;
  } else if (bid < 10240) {
    const int G = (bid - 8192)*256 + tid;
    const int b = G >> 15;
    const int k = (G >> 4) & 2047;
    const int gd = G & 15;
    const float* src = K + ((size_t)b*LL + k)*DD + gd*8;
    float4 f0 = *(const float4*)(src);
    float4 f1 = *(const float4*)(src + 4);
    uint4 o;
    o.x = pkf16(f0.x, f0.y); o.y = pkf16(f0.z, f0.w);
    o.z = pkf16(f1.x, f1.y); o.w = pkf16(f1.z, f1.w);
    const size_t base = ((size_t)b*NT + (k>>6))*16384;
    *(uint4*)(kimg + base + (k&63)*256 + ((gd*16) ^ ((k&15)<<4))) = o;
  } else {
    const int t2 = bid - 10240;
    const int b = t2 >> 7;
    const int rem = t2 & 127;
    const int kt = rem >> 2, dt = rem & 3;
    const int k0 = kt*64, d0 = dt*32;
    const int kl = tid >> 2, dq = (tid & 3)*8;
    const float* src = V + ((size_t)b*LL + k0 + kl)*DD + d0 + dq;
    float4 f0 = *(const float4*)(src);
    float4 f1 = *(const float4*)(src + 4);
    t[dq+0][kl] = f0.x; t[dq+1][kl] = f0.y; t[dq+2][kl] = f0.z; t[dq+3][kl] = f0.w;
    t[dq+4][kl] = f1.x; t[dq+5][kl] = f1.y; t[dq+6][kl] = f1.z; t[dq+7][kl] = f1.w;
    __syncthreads();
    const int dl = tid >> 3, kg = tid & 7;
    const int d = d0 + dl;
    uint4 o;
    o.x = pkf16(t[dl][kg*8+0], t[dl][kg*8+1]);
    o.y = pkf16(t[dl][kg*8+2], t[dl][kg*8+3]);
    o.z = pkf16(t[dl][kg*8+4], t[dl][kg*8+5]);
    o.w = pkf16(t[dl][kg*8+6], t[dl][kg*8+7]);
    const size_t base = ((size_t)b*NT + kt)*16384;
    *(uint4*)(vimg + base + d*128 + ((kg*16) ^ ((d&7)<<4))) = o;
  }
}

// QK^T into aA/aB from KB[buf]
#define QKCOMPUTE(BUFIDX) \
  const char* kb = KB + (BUFIDX)*16384 + krow*256; \
  f32x16 aA, aB; \
  _Pragma("unroll") for (int i=0;i<16;++i){aA[i]=0.f;aB[i]=0.f;} \
  _Pragma("unroll") for (int s=0;s<4;++s){ \
    uint4 af = *(const uint4*)(kb + (((s*2+hi)*16) ^ kswz)); \
    aA = MFMA32(as_f16x8(af), as_f16x8(qf[s]), aA); } \
  _Pragma("unroll") for (int s=4;s<8;++s){ \
    uint4 af = *(const uint4*)(kb + (((s*2+hi)*16) ^ kswz)); \
    aB = MFMA32(as_f16x8(af), as_f16x8(qf[s]), aB); }

#define P1BODY(RR, WN) do { \
  WAITVM(WN); \
  __builtin_amdgcn_s_barrier(); \
  MEMFENCE; \
  stage2(KIMG + imgb + (size_t)(((RR)+1)&31)*16384, KB + (((RR)+1)&1)*16384, soff); \
  SB0; \
  const unsigned bn2 = BMl[2*(((RR)+2)&31)]; \
  SB0; \
  QKCOMPUTE((RR)&1); \
  const unsigned bwh = bcur >> (4*hi); \
  _Pragma("unroll") for (int i=0;i<16;++i){ \
    const float sv = ((bwh>>((i&3)+8*(i>>2)))&1u) ? fmaf(aA[i]+aB[i], SCALE, -CEXP) : -1.0e9f; \
    psum[i&3] += __expf(sv); } \
  bcur = bn1; bn1 = bn2; \
} while(0)

#define P2BODY(RR, WN) do { \
  WAITVM(WN); \
  __builtin_amdgcn_s_barrier(); \
  MEMFENCE; \
  stage2(KIMG + imgb + (size_t)(((RR)+1)&31)*16384, KB + (((RR)+1)&1)*16384, soff); \
  stage2(VIMG + imgb + (size_t)(((RR)+1)&31)*16384, VB + (((RR)+1)&1)*16384, soff); \
  SB0; \
  const unsigned bn2 = BMl[2*(((RR)+2)&31)]; \
  SB0; \
  QKCOMPUTE((RR)&1); \
  const unsigned bwh = bcur >> (4*hi); \
  float pv[16]; \
  _Pragma("unroll") for (int i=0;i<16;++i){ \
    const float sv = ((bwh>>((i&3)+8*(i>>2)))&1u) ? fmaf(aA[i]+aB[i], SCALE, -CEXP) : -1.0e9f; \
    pv[i] = __expf(sv) * inv; } \
  { const float g0 = e ? pv[8]  : pv[0]; \
    const float g1 = e ? pv[9]  : pv[1]; \
    const float g2 = e ? pv[10] : pv[2]; \
    const float g3 = e ? pv[11] : pv[3]; \
    const float g4 = e ? pv[12] : pv[4]; \
    const float g5 = e ? pv[13] : pv[5]; \
    const float g6 = e ? pv[14] : pv[6]; \
    const float g7 = e ? pv[15] : pv[7]; \
    float* prq = Prow + (size_t)(RR)*64 + sub*32 + hi*4 + e*16; \
    float4 o; \
    o.x=g0; o.y=g1; o.z=g2; o.w=g3; *(float4*)(prq)   = o; \
    o.x=g4; o.y=g5; o.z=g6; o.w=g7; *(float4*)(prq+8) = o; } \
  SB0; \
  if (e == 0) { \
    char* pb = PB + p*4096 + sub*2048; \
    uint2 u; \
    u.x = pkrtz(pv[0],pv[1]);   u.y = pkrtz(pv[2],pv[3]);   *(uint2*)(pb + c*16 + hi*8) = u; \
    u.x = pkrtz(pv[4],pv[5]);   u.y = pkrtz(pv[6],pv[7]);   *(uint2*)(pb + (c+32)*16 + hi*8) = u; \
    u.x = pkrtz(pv[8],pv[9]);   u.y = pkrtz(pv[10],pv[11]); *(uint2*)(pb + 1024 + c*16 + hi*8) = u; \
    u.x = pkrtz(pv[12],pv[13]); u.y = pkrtz(pv[14],pv[15]); *(uint2*)(pb + 1024 + (c+32)*16 + hi*8) = u; } \
  asm volatile("s_waitcnt lgkmcnt(0)" ::: "memory"); \
  __builtin_amdgcn_s_barrier(); \
  MEMFENCE; \
  _Pragma("unroll") for (int s2=0;s2<2;++s2){ \
    _Pragma("unroll") for (int k2=0;k2<2;++k2){ \
      const uint4 afr = *(const uint4*)(PB + p*4096 + s2*2048 + k2*1024 + l*16); \
      const int gix = s2*4 + k2*2 + hi; \
      const uint4 b0 = *(const uint4*)(VB + ((RR)&1)*16384 + dv*128 + ((gix*16) ^ ((dv&7)<<4))); \
      ctx0 = MFMA32(as_f16x8(afr), as_f16x8(b0), ctx0); } } \
  bcur = bn1; bn1 = bn2; \
} while(0)

// ---------- main: 2 WGs/CU, WG = (batch, 64 q-rows), 8 waves (e,p,sub), two passes ----------
__global__ __launch_bounds__(512, 4) void attn_main(
    const float* __restrict__ Q, const unsigned int* __restrict__ BM,
    const unsigned char* __restrict__ KIMG, const unsigned char* __restrict__ VIMG,
    float* __restrict__ ctxout, float* __restrict__ pout)
{
  extern __shared__ char lds[];
  char* KB = lds + OFF_KB;
  char* VB = lds + OFF_VB;
  char* PB = lds + OFF_PB;
  float* RED = (float*)(lds + OFF_RED);

  const int tid = threadIdx.x;
  const int w = tid >> 6, l = tid & 63;
  const int c = l & 31, hi = l >> 5;
  const int e = w >> 2, p = (w >> 1) & 1, sub = w & 1;

  const int bid = blockIdx.x;
  const int xcd = bid & 7, jj = bid >> 3;          // jj 0..63
  const int b = xcd*2 + (jj >> 5);
  const int q0 = (jj & 31) * 64;
  const int qrow = q0 + p*32 + c;

  // Q fragments (fp16)
  uint4 qf[8];
  const float* qp0 = Q + ((size_t)b*LL + qrow)*DD;
#pragma unroll
  for (int s = 0; s < 8; ++s) {
    const float4 f0 = *(const float4*)(qp0 + s*16 + hi*8);
    const float4 f1 = *(const float4*)(qp0 + s*16 + hi*8 + 4);
    uint4 qv;
    qv.x = pkf16(f0.x, f0.y); qv.y = pkf16(f0.z, f0.w);
    qv.z = pkf16(f1.x, f1.y); qv.w = pkf16(f1.z, f1.w);
    qf[s] = qv;
  }

  const size_t imgb = ((size_t)b * NT) * 16384;
  const int soff = w*2048 + l*16;
  const unsigned int* BMl = BM + ((size_t)b*LL + qrow)*64 + sub;
  const int krow = sub*32 + c;
  const int kswz = (c & 15) << 4;
  const int dv = (sub*2 + e)*32 + c;               // this wave's d-column for PV/ctx

  // ---------------- PASS 1: row sums of exp(S - CEXP) ----------------
  stage2(KIMG + imgb + 0*16384, KB + 0*16384, soff); SB0;
  unsigned bcur = BMl[0]; SB0;
  unsigned bn1 = BMl[2]; SB0;

  float psum[4] = {0.f, 0.f, 0.f, 0.f};
  P1BODY(0, 2);
#pragma unroll 1
  for (int r = 1; r < 32; ++r) {
    P1BODY(r, 1);
  }
  float sum = (psum[0] + psum[1]) + (psum[2] + psum[3]);
  sum += __shfl_xor(sum, 32);
  __syncthreads();                       // full drain (incl. wrap stage)
  if (l < 32 && e == 0) RED[(p*2+sub)*32 + c] = sum;
  __syncthreads();
  float tot = RED[(p*2+sub)*32 + c] + RED[(p*2+(1-sub))*32 + c];
  tot = fmaxf(tot, 1e-35f);
  const float inv = 1.0f / tot;
  __syncthreads();

  // ---------------- PASS 2: P = exp(S-CEXP)*inv, write P, ctx = P*V ----------------
  stage2(KIMG + imgb + 0*16384, KB + 0*16384, soff);
  stage2(VIMG + imgb + 0*16384, VB + 0*16384, soff); SB0;
  bcur = BMl[0]; SB0;
  bn1 = BMl[2]; SB0;

  f32x16 ctx0;
#pragma unroll
  for (int i = 0; i < 16; ++i) ctx0[i] = 0.f;
  float* Prow = pout + ((size_t)b*LL + qrow)*LL;

  P2BODY(0, 2);
#pragma unroll 1
  for (int r = 1; r < 32; ++r) {
    P2BODY(r, 3);
  }

  WAITVM(0);                             // drain wrap stage + stores before epilogue
  // ---- ctx epilogue
#pragma unroll
  for (int reg = 0; reg < 16; ++reg) {
    const int q = q0 + p*32 + (reg&3) + 8*(reg>>2) + 4*hi;
    ctxout[((size_t)b*LL + q)*DD + dv] = ctx0[reg];
  }
}

// ---------- fallback (ws too small): simple correct version ----------
__global__ __launch_bounds__(256) void attn_naive(
    const float* __restrict__ Q, const float* __restrict__ K,
    const float* __restrict__ V, const int* __restrict__ M,
    float* __restrict__ ctx, float* __restrict__ pout)
{
  const int b = blockIdx.x >> 11;
  const int q = blockIdx.x & (LL-1);
  __shared__ float s[LL];
  __shared__ float red[256];
  const int tid = threadIdx.x;
  const float* qp = Q + ((size_t)b*LL + q)*DD;
  for (int kk = tid; kk < LL; kk += 256) {
    const float* kp = K + ((size_t)b*LL + kk)*DD;
    float a = 0.f;
    for (int d = 0; d < DD; ++d) a += qp[d]*kp[d];
    s[kk] = M[((size_t)b*LL + q)*LL + kk] ? a*SCALE : -1e9f;
  }
  __syncthreads();
  float mx = -3e38f;
  for (int kk = tid; kk < LL; kk += 256) mx = fmaxf(mx, s[kk]);
  red[tid] = mx; __syncthreads();
  for (int o = 128; o >= 1; o >>= 1) {
    if (tid < o) red[tid] = fmaxf(red[tid], red[tid+o]);
    __syncthreads();
  }
  const float mrow = red[0]; __syncthreads();
  float sm = 0.f;
  for (int kk = tid; kk < LL; kk += 256) { float e2 = __expf(s[kk]-mrow); s[kk] = e2; sm += e2; }
  red[tid] = sm; __syncthreads();
  for (int o = 128; o >= 1; o >>= 1) {
    if (tid < o) red[tid] += red[tid+o];
    __syncthreads();
  }
  const float inv = 1.0f / red[0]; __syncthreads();
  float* prow = pout + ((size_t)b*LL + q)*LL;
  for (int kk = tid; kk < LL; kk += 256) { s[kk] *= inv; prow[kk] = s[kk]; }
  __syncthreads();
  if (tid < DD) {
    float a = 0.f;
    for (int kk = 0; kk < LL; ++kk) a += s[kk]*V[((size_t)b*LL + kk)*DD + tid];
    ctx[((size_t)b*LL + q)*DD + tid] = a;
  }
}

extern "C" void kernel_launch(void* const* d_in, const int* in_sizes, int n_in,
                              void* d_out, int out_size, void* d_ws, size_t ws_size,
                              hipStream_t stream) {
  (void)in_sizes; (void)n_in; (void)out_size;
  const float* Q = (const float*)d_in[0];
  const float* K = (const float*)d_in[1];
  const float* V = (const float*)d_in[2];
  const int*   M = (const int*)d_in[3];
  float* ctx  = (float*)d_out;
  float* pout = ctx + (size_t)BB*LL*DD;
  const size_t IMG = (size_t)BB*NT*16384;        // 8 MB per image
  const size_t NBM = (size_t)BB*LL*(LL/32);      // 2.1M words = 8 MB
  const size_t WS_NEED = IMG*2 + NBM*4;
  if (ws_size >= WS_NEED) {
    unsigned char* kimg = (unsigned char*)d_ws;
    unsigned char* vimg = kimg + IMG;
    unsigned int*  bmw  = (unsigned int*)(vimg + IMG);
    hipFuncSetAttribute(reinterpret_cast<const void*>(attn_main),
                        hipFuncAttributeMaxDynamicSharedMemorySize, LDS_MAIN);
    prep_all<<<12288, 256, 0, stream>>>(K, V, M, kimg, vimg, bmw);
    attn_main<<<512, 512, LDS_MAIN, stream>>>(Q, bmw, kimg, vimg, ctx, pout);
  } else {
    attn_naive<<<BB*LL, 256, 0, stream>>>(Q, K, V, M, ctx, pout);
  }
}

// Round 10
// 216.813 us; speedup vs baseline: 1.0519x; 1.0519x over previous
//
#include <hip/hip_runtime.h>
#include <hip/hip_bf16.h>
#include <hip/hip_fp16.h>

#define BB 16
#define LL 2048
#define DD 128
#define SCALE 0.08838834764831845f
#define CEXP 12.0f
#define NT 32        // k-tiles of 64

typedef _Float16 f16x8 __attribute__((ext_vector_type(8)));
typedef float f32x16 __attribute__((ext_vector_type(16)));

#define MFMA32(a,b,c) __builtin_amdgcn_mfma_f32_32x32x16_f16((a),(b),(c),0,0,0)

// LDS map (main): KB 4x16K | MB 2x32K | PB 16K | RED 1K  = 148480
#define OFF_KB   0
#define OFF_MB   65536
#define OFF_PB   131072
#define OFF_RED  147456
#define LDS_MAIN 148480
// pass 2 reuses MB as VB (V double-buffer lives at OFF_MB, 4x16K)
#define OFF_VB   65536

#define WAITVM(N)  asm volatile("s_waitcnt vmcnt(" #N ")" ::: "memory")
#define MEMFENCE   asm volatile("" ::: "memory")
#define SB0        __builtin_amdgcn_sched_barrier(0)

__device__ __forceinline__ f16x8 as_f16x8(uint4 v){
  union { uint4 u; f16x8 h; } x; x.u = v; return x.h;
}
__device__ __forceinline__ unsigned pkf16(float a, float b){
  __half ha = __float2half_rn(a), hb = __float2half_rn(b);
  return (unsigned)__half_as_ushort(ha) | ((unsigned)__half_as_ushort(hb) << 16);
}
__device__ __forceinline__ unsigned pkrtz(float a, float b){
  union { decltype(__builtin_amdgcn_cvt_pkrtz(0.f, 0.f)) h; unsigned u; } x;
  x.h = __builtin_amdgcn_cvt_pkrtz(a, b);
  return x.u;
}
__device__ __forceinline__ void stage16(const unsigned char* g, char* l){
  __builtin_amdgcn_global_load_lds(
      (const __attribute__((address_space(1))) void*)g,
      (__attribute__((address_space(3))) void*)l, 16, 0, 0);
}
__device__ __forceinline__ void stage2(const unsigned char* g, char* l, int soff){
  stage16(g + soff, l + soff);
  stage16(g + soff + 1024, l + soff + 1024);
}
// mask stage: 4 calls, j-th covers staging rows j*32..j*32+31 (32 KB total / round)
__device__ __forceinline__ void mstage(const unsigned char* msrc, char* mdst, int roff){
  stage16(msrc + roff,          mdst);
  stage16(msrc + roff + 262144, mdst + 8192);
  stage16(msrc + roff + 524288, mdst + 16384);
  stage16(msrc + roff + 786432, mdst + 24576);
}

// ---------- prep: K -> fp16 swizzled k-major image | V -> fp16 swizzled d-major ----------
// K image tile (b,t): byte = klocal*256 + ((gd*16)^((klocal&15)<<4)), gd = d/8
// V image tile (b,t): byte = d*128 + ((gk*16)^((d&7)<<4)), gk covers k 8*gk..+7
__global__ __launch_bounds__(256) void prep_img(
    const float* __restrict__ K, const float* __restrict__ V,
    unsigned char* __restrict__ kimg, unsigned char* __restrict__ vimg)
{
  __shared__ float t[32][65];
  const int bid = blockIdx.x, tid = threadIdx.x;
  if (bid < 2048) {
    const int G = bid*256 + tid;
    const int b = G >> 15;
    const int k = (G >> 4) & 2047;
    const int gd = G & 15;
    const float* src = K + ((size_t)b*LL + k)*DD + gd*8;
    float4 f0 = *(const float4*)(src);
    float4 f1 = *(const float4*)(src + 4);
    uint4 o;
    o.x = pkf16(f0.x, f0.y); o.y = pkf16(f0.z, f0.w);
    o.z = pkf16(f1.x, f1.y); o.w = pkf16(f1.z, f1.w);
    const size_t base = ((size_t)b*NT + (k>>6))*16384;
    *(uint4*)(kimg + base + (k&63)*256 + ((gd*16) ^ ((k&15)<<4))) = o;
  } else {
    const int t2 = bid - 2048;
    const int b = t2 >> 7;
    const int rem = t2 & 127;
    const int kt = rem >> 2, dt = rem & 3;
    const int k0 = kt*64, d0 = dt*32;
    const int kl = tid >> 2, dq = (tid & 3)*8;
    const float* src = V + ((size_t)b*LL + k0 + kl)*DD + d0 + dq;
    float4 f0 = *(const float4*)(src);
    float4 f1 = *(const float4*)(src + 4);
    t[dq+0][kl] = f0.x; t[dq+1][kl] = f0.y; t[dq+2][kl] = f0.z; t[dq+3][kl] = f0.w;
    t[dq+4][kl] = f1.x; t[dq+5][kl] = f1.y; t[dq+6][kl] = f1.z; t[dq+7][kl] = f1.w;
    __syncthreads();
    const int dl = tid >> 3, kg = tid & 7;
    const int d = d0 + dl;
    uint4 o;
    o.x = pkf16(t[dl][kg*8+0], t[dl][kg*8+1]);
    o.y = pkf16(t[dl][kg*8+2], t[dl][kg*8+3]);
    o.z = pkf16(t[dl][kg*8+4], t[dl][kg*8+5]);
    o.w = pkf16(t[dl][kg*8+6], t[dl][kg*8+7]);
    const size_t base = ((size_t)b*NT + kt)*16384;
    *(uint4*)(vimg + base + d*128 + ((kg*16) ^ ((d&7)<<4))) = o;
  }
}

// QK^T into aA/aB from KB[buf]
#define QKCOMPUTE(BUFIDX) \
  const char* kb = KB + (BUFIDX)*16384 + krow*256; \
  f32x16 aA, aB; \
  _Pragma("unroll") for (int i=0;i<16;++i){aA[i]=0.f;aB[i]=0.f;} \
  _Pragma("unroll") for (int s=0;s<4;++s){ \
    uint4 af = *(const uint4*)(kb + (((s*2+hi)*16) ^ kswz)); \
    aA = MFMA32(as_f16x8(af), as_f16x8(qf[s]), aA); } \
  _Pragma("unroll") for (int s=4;s<8;++s){ \
    uint4 af = *(const uint4*)(kb + (((s*2+hi)*16) ^ kswz)); \
    aB = MFMA32(as_f16x8(af), as_f16x8(qf[s]), aB); }

// pass 1: mask staged via global_load_lds; per-round issues: M(4) K(2) BMstore(1)
#define P1BODY(RR, WN) do { \
  WAITVM(WN); \
  __builtin_amdgcn_s_barrier(); \
  MEMFENCE; \
  mstage(msrc, mdw + (((RR)+1)&1)*32768, (((RR)+1)&31)*256); \
  SB0; \
  stage2(KIMG + imgb + (size_t)(((RR)+3)&31)*16384, KB + (((RR)+3)&3)*16384, soff); \
  SB0; \
  QKCOMPUTE((RR)&3); \
  const char* mb = mrd + ((RR)&1)*32768; \
  const int4 m0 = *(const int4*)(mb + mo0); \
  const int4 m1 = *(const int4*)(mb + mo1); \
  const int4 m2 = *(const int4*)(mb + mo2); \
  const int4 m3 = *(const int4*)(mb + mo3); \
  const unsigned w16 = (m0.x?0x1u:0u)|(m0.y?0x2u:0u)|(m0.z?0x4u:0u)|(m0.w?0x8u:0u) \
                     | (m1.x?0x100u:0u)|(m1.y?0x200u:0u)|(m1.z?0x400u:0u)|(m1.w?0x800u:0u) \
                     | (m2.x?0x10000u:0u)|(m2.y?0x20000u:0u)|(m2.z?0x40000u:0u)|(m2.w?0x80000u:0u) \
                     | (m3.x?0x1000000u:0u)|(m3.y?0x2000000u:0u)|(m3.z?0x4000000u:0u)|(m3.w?0x8000000u:0u); \
  { const unsigned pw = __shfl_xor(w16, 32); \
    if (l < 32) BM[bmbase + (RR)*2] = w16 | (pw << 4); } \
  _Pragma("unroll") for (int i=0;i<16;++i){ \
    const float sv = ((w16>>((i&3)+8*(i>>2)))&1u) ? fmaf(aA[i]+aB[i], SCALE, -CEXP) : -1.0e9f; \
    psum[i&3] += __expf(sv); } \
} while(0)

#define P2BODY(RR, NTOK) do { \
  WAITVM(NTOK); \
  __builtin_amdgcn_s_barrier(); \
  MEMFENCE; \
  const unsigned bn2 = BM[bmbase + 2*(((RR)+2)&31)]; \
  SB0; \
  stage2(KIMG + imgb + (size_t)(((RR)+3)&31)*16384, KB + (((RR)+3)&3)*16384, soff); \
  stage2(VIMG + imgb + (size_t)(((RR)+3)&31)*16384, VB + (((RR)+3)&3)*16384, soff); \
  SB0; \
  QKCOMPUTE((RR)&3); \
  const unsigned bwh = bcur >> (4*hi); \
  float pv[16]; \
  _Pragma("unroll") for (int i=0;i<16;++i){ \
    const float sv = ((bwh>>((i&3)+8*(i>>2)))&1u) ? fmaf(aA[i]+aB[i], SCALE, -CEXP) : -1.0e9f; \
    pv[i] = __expf(sv) * inv; } \
  { float* pr = Prow + (size_t)(RR)*64 + sub*32 + hi*4; \
    float4 o; \
    o.x=pv[0];  o.y=pv[1];  o.z=pv[2];  o.w=pv[3];  *(float4*)(pr)    = o; \
    o.x=pv[4];  o.y=pv[5];  o.z=pv[6];  o.w=pv[7];  *(float4*)(pr+8)  = o; \
    o.x=pv[8];  o.y=pv[9];  o.z=pv[10]; o.w=pv[11]; *(float4*)(pr+16) = o; \
    o.x=pv[12]; o.y=pv[13]; o.z=pv[14]; o.w=pv[15]; *(float4*)(pr+24) = o; } \
  SB0; \
  { char* pb = PB + p*4096 + sub*2048; \
    uint2 u; \
    u.x = pkrtz(pv[0],pv[1]);   u.y = pkrtz(pv[2],pv[3]);   *(uint2*)(pb + c*16 + hi*8) = u; \
    u.x = pkrtz(pv[4],pv[5]);   u.y = pkrtz(pv[6],pv[7]);   *(uint2*)(pb + (c+32)*16 + hi*8) = u; \
    u.x = pkrtz(pv[8],pv[9]);   u.y = pkrtz(pv[10],pv[11]); *(uint2*)(pb + 1024 + c*16 + hi*8) = u; \
    u.x = pkrtz(pv[12],pv[13]); u.y = pkrtz(pv[14],pv[15]); *(uint2*)(pb + 1024 + (c+32)*16 + hi*8) = u; } \
  asm volatile("s_waitcnt lgkmcnt(0)" ::: "memory"); \
  __builtin_amdgcn_s_barrier(); \
  MEMFENCE; \
  _Pragma("unroll") for (int s2=0;s2<2;++s2){ \
    _Pragma("unroll") for (int k2=0;k2<2;++k2){ \
      const uint4 afr = *(const uint4*)(PB + p*4096 + s2*2048 + k2*1024 + l*16); \
      const int gix = s2*4 + k2*2 + hi; \
      const int d0v = sub*64 + c; \
      const uint4 b0 = *(const uint4*)(VB + ((RR)&3)*16384 + d0v*128 + ((gix*16) ^ ((d0v&7)<<4))); \
      ctx0 = MFMA32(as_f16x8(afr), as_f16x8(b0), ctx0); \
      const int d1v = sub*64 + 32 + c; \
      const uint4 b1 = *(const uint4*)(VB + ((RR)&3)*16384 + d1v*128 + ((gix*16) ^ ((d1v&7)<<4))); \
      ctx1 = MFMA32(as_f16x8(afr), as_f16x8(b1), ctx1); } } \
  bcur = bn1; bn1 = bn2; \
} while(0)

// ---------- main: 1 WG/CU = (batch, 128 q-rows), 8 waves, two passes ----------
__global__ __launch_bounds__(512) void attn_main(
    const float* __restrict__ Q, const int* __restrict__ M,
    unsigned int* __restrict__ BM,
    const unsigned char* __restrict__ KIMG, const unsigned char* __restrict__ VIMG,
    float* __restrict__ ctxout, float* __restrict__ pout)
{
  extern __shared__ char lds[];
  char* KB = lds + OFF_KB;
  char* VB = lds + OFF_VB;       // pass 2 only (aliases MB)
  char* PB = lds + OFF_PB;
  float* RED = (float*)(lds + OFF_RED);

  const int tid = threadIdx.x;
  const int w = tid >> 6, l = tid & 63;
  const int c = l & 31, hi = l >> 5;
  const int p = w >> 1, sub = w & 1;

  const int bid = blockIdx.x;
  const int xcd = bid & 7, jj = bid >> 3;
  const int b = xcd*2 + (jj >> 4);
  const int q0 = (jj & 15) * 128;
  const int qrow = q0 + p*32 + c;

  // Q fragments (fp16)
  uint4 qf[8];
  const float* qp0 = Q + ((size_t)b*LL + qrow)*DD;
#pragma unroll
  for (int s = 0; s < 8; ++s) {
    const float4 f0 = *(const float4*)(qp0 + s*16 + hi*8);
    const float4 f1 = *(const float4*)(qp0 + s*16 + hi*8 + 4);
    uint4 qv;
    qv.x = pkf16(f0.x, f0.y); qv.y = pkf16(f0.z, f0.w);
    qv.z = pkf16(f1.x, f1.y); qv.w = pkf16(f1.z, f1.w);
    qf[s] = qv;
  }

  const size_t imgb = ((size_t)b * NT) * 16384;
  const int soff = w*2048 + l*16;
  const size_t bmbase = ((size_t)b*LL + qrow)*64 + sub;
  const int krow = sub*32 + c;
  const int kswz = (c & 15) << 4;

  // mask staging geometry (pass 1): stage row (j=0) = w*4 + (l>>4); chunk swizzle ^= row&15
  const int srow = w*4 + (l >> 4);
  const unsigned char* msrc = (const unsigned char*)M
      + ((size_t)(b*LL + q0 + srow))*LL*4 + (size_t)(((l & 15) ^ (srow & 15)) * 16);
  char* mdw = lds + OFF_MB + w*1024 + l*16;        // + buf*32768 + j*8192 in mstage
  // mask read geometry: thread reads 4 int4 for (row = p*32+c, cols sub*32+hi*4+{0,8,16,24})
  const int rowc = p*32 + c;
  const char* mrd = lds + OFF_MB + rowc*256;
  const int mswz = rowc & 15;
  const int cbx = sub*8 + hi;
  const int mo0 = ((cbx+0)^mswz)*16, mo1 = ((cbx+2)^mswz)*16;
  const int mo2 = ((cbx+4)^mswz)*16, mo3 = ((cbx+6)^mswz)*16;

  // ---------------- PASS 1: row sums of exp(S - CEXP); builds bitmask for pass 2 ----------------
  stage2(KIMG + imgb + 0*16384, KB + 0*16384, soff); SB0;
  mstage(msrc, mdw + 0*32768, 0*256); SB0;
  stage2(KIMG + imgb + 1*16384, KB + 1*16384, soff); SB0;
  stage2(KIMG + imgb + 2*16384, KB + 2*16384, soff); SB0;

  float psum[4] = {0.f, 0.f, 0.f, 0.f};
  P1BODY(0, 4);
#pragma unroll 1
  for (int r = 1; r < 32; ++r) {
    P1BODY(r, 3);
  }
  float sum = (psum[0] + psum[1]) + (psum[2] + psum[3]);
  sum += __shfl_xor(sum, 32);
  __syncthreads();                       // full drain; BM stores visible
  if (l < 32) RED[(p*2+sub)*32 + c] = sum;
  __syncthreads();
  float tot = RED[(p*2+sub)*32 + c] + RED[(p*2+(1-sub))*32 + c];
  tot = fmaxf(tot, 1e-35f);
  const float inv = 1.0f / tot;
  __syncthreads();

  // ---------------- PASS 2: P = exp(S-CEXP)*inv, write P, ctx = P*V ----------------
  stage2(KIMG + imgb + 0*16384, KB + 0*16384, soff);
  stage2(VIMG + imgb + 0*16384, VB + 0*16384, soff); SB0;
  unsigned bcur = BM[bmbase]; SB0;
  stage2(KIMG + imgb + 1*16384, KB + 1*16384, soff);
  stage2(VIMG + imgb + 1*16384, VB + 1*16384, soff); SB0;
  unsigned bn1 = BM[bmbase + 2]; SB0;
  stage2(KIMG + imgb + 2*16384, KB + 2*16384, soff);
  stage2(VIMG + imgb + 2*16384, VB + 2*16384, soff); SB0;

  f32x16 ctx0, ctx1;
#pragma unroll
  for (int i = 0; i < 16; ++i) { ctx0[i] = 0.f; ctx1[i] = 0.f; }
  float* Prow = pout + ((size_t)b*LL + qrow)*LL;

  P2BODY(0, 10);
  P2BODY(1, 14);
  P2BODY(2, 18);
#pragma unroll 1
  for (int r = 3; r < 32; ++r) {
    P2BODY(r, 22);
  }

  // ---- ctx epilogue
#pragma unroll
  for (int reg = 0; reg < 16; ++reg) {
    const int q = q0 + p*32 + (reg&3) + 8*(reg>>2) + 4*hi;
    float* cr = ctxout + ((size_t)b*LL + q)*DD;
    cr[sub*64 + c]      = ctx0[reg];
    cr[sub*64 + 32 + c] = ctx1[reg];
  }
}

// ---------- fallback (ws too small): simple correct version ----------
__global__ __launch_bounds__(256) void attn_naive(
    const float* __restrict__ Q, const float* __restrict__ K,
    const float* __restrict__ V, const int* __restrict__ M,
    float* __restrict__ ctx, float* __restrict__ pout)
{
  const int b = blockIdx.x >> 11;
  const int q = blockIdx.x & (LL-1);
  __shared__ float s[LL];
  __shared__ float red[256];
  const int tid = threadIdx.x;
  const float* qp = Q + ((size_t)b*LL + q)*DD;
  for (int kk = tid; kk < LL; kk += 256) {
    const float* kp = K + ((size_t)b*LL + kk)*DD;
    float a = 0.f;
    for (int d = 0; d < DD; ++d) a += qp[d]*kp[d];
    s[kk] = M[((size_t)b*LL + q)*LL + kk] ? a*SCALE : -1e9f;
  }
  __syncthreads();
  float mx = -3e38f;
  for (int kk = tid; kk < LL; kk += 256) mx = fmaxf(mx, s[kk]);
  red[tid] = mx; __syncthreads();
  for (int o = 128; o >= 1; o >>= 1) {
    if (tid < o) red[tid] = fmaxf(red[tid], red[tid+o]);
    __syncthreads();
  }
  const float mrow = red[0]; __syncthreads();
  float sm = 0.f;
  for (int kk = tid; kk < LL; kk += 256) { float e = __expf(s[kk]-mrow); s[kk] = e; sm += e; }
  red[tid] = sm; __syncthreads();
  for (int o = 128; o >= 1; o >>= 1) {
    if (tid < o) red[tid] += red[tid+o];
    __syncthreads();
  }
  const float inv = 1.0f / red[0]; __syncthreads();
  float* prow = pout + ((size_t)b*LL + q)*LL;
  for (int kk = tid; kk < LL; kk += 256) { s[kk] *= inv; prow[kk] = s[kk]; }
  __syncthreads();
  if (tid < DD) {
    float a = 0.f;
    for (int kk = 0; kk < LL; ++kk) a += s[kk]*V[((size_t)b*LL + kk)*DD + tid];
    ctx[((size_t)b*LL + q)*DD + tid] = a;
  }
}

extern "C" void kernel_launch(void* const* d_in, const int* in_sizes, int n_in,
                              void* d_out, int out_size, void* d_ws, size_t ws_size,
                              hipStream_t stream) {
  (void)in_sizes; (void)n_in; (void)out_size;
  const float* Q = (const float*)d_in[0];
  const float* K = (const float*)d_in[1];
  const float* V = (const float*)d_in[2];
  const int*   M = (const int*)d_in[3];
  float* ctx  = (float*)d_out;
  float* pout = ctx + (size_t)BB*LL*DD;
  const size_t IMG = (size_t)BB*NT*16384;        // 8 MB per image
  const size_t NBM = (size_t)BB*LL*(LL/32);      // 2.1M words = 8 MB
  const size_t WS_NEED = IMG*2 + NBM*4;
  if (ws_size >= WS_NEED) {
    unsigned char* kimg = (unsigned char*)d_ws;
    unsigned char* vimg = kimg + IMG;
    unsigned int*  bmw  = (unsigned int*)(vimg + IMG);
    hipFuncSetAttribute(reinterpret_cast<const void*>(attn_main),
                        hipFuncAttributeMaxDynamicSharedMemorySize, LDS_MAIN);
    prep_img<<<4096, 256, 0, stream>>>(K, V, kimg, vimg);
    attn_main<<<256, 512, LDS_MAIN, stream>>>(Q, M, bmw, kimg, vimg, ctx, pout);
  } else {
    attn_naive<<<BB*LL, 256, 0, stream>>>(Q, K, V, M, ctx, pout);
  }
}

// Round 11
// 203.211 us; speedup vs baseline: 1.1223x; 1.0669x over previous
//
#include <hip/hip_runtime.h>
#include <hip/hip_bf16.h>
#include <hip/hip_fp16.h>

#define BB 16
#define LL 2048
#define DD 128
#define SCALE 0.08838834764831845f
#define CEXP 12.0f
#define NT 32        // k-tiles of 64

typedef _Float16 f16x8 __attribute__((ext_vector_type(8)));
typedef float f32x16 __attribute__((ext_vector_type(16)));

#define MFMA32(a,b,c) __builtin_amdgcn_mfma_f32_32x32x16_f16((a),(b),(c),0,0,0)

// LDS map (main): KB 4x16K | VB 4x16K | PB 16K | RED 1K
#define OFF_KB   0
#define OFF_VB   65536
#define OFF_PB   131072
#define OFF_RED  147456
#define LDS_MAIN 148480

#define WAITVM(N)  asm volatile("s_waitcnt vmcnt(" #N ")" ::: "memory")
#define WAITLGKM0  asm volatile("s_waitcnt lgkmcnt(0)" ::: "memory")
#define MEMFENCE   asm volatile("" ::: "memory")
#define SB0        __builtin_amdgcn_sched_barrier(0)

__device__ __forceinline__ f16x8 as_f16x8(uint4 v){
  union { uint4 u; f16x8 h; } x; x.u = v; return x.h;
}
__device__ __forceinline__ unsigned pkf16(float a, float b){
  __half ha = __float2half_rn(a), hb = __float2half_rn(b);
  return (unsigned)__half_as_ushort(ha) | ((unsigned)__half_as_ushort(hb) << 16);
}
__device__ __forceinline__ unsigned pkrtz(float a, float b){
  union { decltype(__builtin_amdgcn_cvt_pkrtz(0.f, 0.f)) h; unsigned u; } x;
  x.h = __builtin_amdgcn_cvt_pkrtz(a, b);
  return x.u;
}
__device__ __forceinline__ float h2f(unsigned short u){
  return __half2float(__ushort_as_half(u));
}
__device__ __forceinline__ void stage16(const unsigned char* g, char* l){
  __builtin_amdgcn_global_load_lds(
      (const __attribute__((address_space(1))) void*)g,
      (__attribute__((address_space(3))) void*)l, 16, 0, 0);
}
__device__ __forceinline__ void stage2(const unsigned char* g, char* l, int soff){
  stage16(g + soff, l + soff);
  stage16(g + soff + 1024, l + soff + 1024);
}

// ---------- prep: mask->bits | K -> fp16 swizzled k-major image | V -> fp16 swizzled d-major ----------
// K image tile (b,t): byte = klocal*256 + ((gd*16)^((klocal&15)<<4)), gd = d/8
// V image tile (b,t): byte = d*128 + ((gk*16)^((d&7)<<4)), gk covers k 8*gk..+7
__global__ __launch_bounds__(256) void prep_all(
    const float* __restrict__ K, const float* __restrict__ V,
    const int* __restrict__ M,
    unsigned char* __restrict__ kimg, unsigned char* __restrict__ vimg,
    unsigned int* __restrict__ bm)
{
  __shared__ float t[32][65];
  const int bid = blockIdx.x, tid = threadIdx.x;
  if (bid < 8192) {
    const size_t wi = (size_t)bid * 256 + tid;      // word index, 2^21 total
    const int* mp = M + wi * 32;
    unsigned int wrd = 0;
#pragma unroll
    for (int j = 0; j < 8; ++j) {
      int4 v = *(const int4*)(mp + j*4);
      wrd |= (v.x ? 1u : 0u) << (4*j)
          |  (v.y ? 1u : 0u) << (4*j+1)
          |  (v.z ? 1u : 0u) << (4*j+2)
          |  (v.w ? 1u : 0u) << (4*j+3);
    }
    bm[wi] = wrd;
  } else if (bid < 10240) {
    const int G = (bid - 8192)*256 + tid;
    const int b = G >> 15;
    const int k = (G >> 4) & 2047;
    const int gd = G & 15;
    const float* src = K + ((size_t)b*LL + k)*DD + gd*8;
    float4 f0 = *(const float4*)(src);
    float4 f1 = *(const float4*)(src + 4);
    uint4 o;
    o.x = pkf16(f0.x, f0.y); o.y = pkf16(f0.z, f0.w);
    o.z = pkf16(f1.x, f1.y); o.w = pkf16(f1.z, f1.w);
    const size_t base = ((size_t)b*NT + (k>>6))*16384;
    *(uint4*)(kimg + base + (k&63)*256 + ((gd*16) ^ ((k&15)<<4))) = o;
  } else {
    const int t2 = bid - 10240;
    const int b = t2 >> 7;
    const int rem = t2 & 127;
    const int kt = rem >> 2, dt = rem & 3;
    const int k0 = kt*64, d0 = dt*32;
    const int kl = tid >> 2, dq = (tid & 3)*8;
    const float* src = V + ((size_t)b*LL + k0 + kl)*DD + d0 + dq;
    float4 f0 = *(const float4*)(src);
    float4 f1 = *(const float4*)(src + 4);
    t[dq+0][kl] = f0.x; t[dq+1][kl] = f0.y; t[dq+2][kl] = f0.z; t[dq+3][kl] = f0.w;
    t[dq+4][kl] = f1.x; t[dq+5][kl] = f1.y; t[dq+6][kl] = f1.z; t[dq+7][kl] = f1.w;
    __syncthreads();
    const int dl = tid >> 3, kg = tid & 7;
    const int d = d0 + dl;
    uint4 o;
    o.x = pkf16(t[dl][kg*8+0], t[dl][kg*8+1]);
    o.y = pkf16(t[dl][kg*8+2], t[dl][kg*8+3]);
    o.z = pkf16(t[dl][kg*8+4], t[dl][kg*8+5]);
    o.w = pkf16(t[dl][kg*8+6], t[dl][kg*8+7]);
    const size_t base = ((size_t)b*NT + kt)*16384;
    *(uint4*)(vimg + base + d*128 + ((kg*16) ^ ((d&7)<<4))) = o;
  }
}

// QK^T into aA/aB from KB[buf]
#define QKCOMPUTE(BUFIDX) \
  const char* kb = KB + (BUFIDX)*16384 + krow*256; \
  f32x16 aA, aB; \
  _Pragma("unroll") for (int i=0;i<16;++i){aA[i]=0.f;aB[i]=0.f;} \
  _Pragma("unroll") for (int s=0;s<4;++s){ \
    uint4 af = *(const uint4*)(kb + (((s*2+hi)*16) ^ kswz)); \
    aA = MFMA32(as_f16x8(af), as_f16x8(qf[s]), aA); } \
  _Pragma("unroll") for (int s=4;s<8;++s){ \
    uint4 af = *(const uint4*)(kb + (((s*2+hi)*16) ^ kswz)); \
    aB = MFMA32(as_f16x8(af), as_f16x8(qf[s]), aB); }

#define P1BODY(RR) do { \
  WAITVM(6); \
  __builtin_amdgcn_s_barrier(); \
  MEMFENCE; \
  const unsigned bn2 = BMl[2*(((RR)+2)&31)]; \
  SB0; \
  stage2(KIMG + imgb + (size_t)(((RR)+3)&31)*16384, KB + (((RR)+3)&3)*16384, soff); \
  SB0; \
  QKCOMPUTE((RR)&3); \
  const unsigned bwh = bcur >> (4*hi); \
  _Pragma("unroll") for (int i=0;i<16;++i){ \
    const float sv = ((bwh>>((i&3)+8*(i>>2)))&1u) ? fmaf(aA[i]+aB[i], SCALE, -CEXP) : -1.0e9f; \
    psum[i&3] += __expf(sv); } \
  bcur = bn1; bn1 = bn2; \
} while(0)

#define P2BODY(RR, NTOK) do { \
  WAITVM(NTOK); \
  __builtin_amdgcn_s_barrier(); \
  MEMFENCE; \
  const unsigned bn2 = BMl[2*(((RR)+2)&31)]; \
  SB0; \
  stage2(KIMG + imgb + (size_t)(((RR)+3)&31)*16384, KB + (((RR)+3)&3)*16384, soff); \
  stage2(VIMG + imgb + (size_t)(((RR)+3)&31)*16384, VB + (((RR)+3)&3)*16384, soff); \
  SB0; \
  QKCOMPUTE((RR)&3); \
  const unsigned bwh = bcur >> (4*hi); \
  float pv[16]; \
  _Pragma("unroll") for (int i=0;i<16;++i){ \
    const float sv = ((bwh>>((i&3)+8*(i>>2)))&1u) ? fmaf(aA[i]+aB[i], SCALE, -CEXP) : -1.0e9f; \
    pv[i] = __expf(sv) * inv; } \
  { char* pb = PB + p*4096 + sub*2048; \
    uint2 u; \
    u.x = pkrtz(pv[0],pv[1]);   u.y = pkrtz(pv[2],pv[3]);   *(uint2*)(pb + c*16 + hi*8) = u; \
    u.x = pkrtz(pv[4],pv[5]);   u.y = pkrtz(pv[6],pv[7]);   *(uint2*)(pb + (c+32)*16 + hi*8) = u; \
    u.x = pkrtz(pv[8],pv[9]);   u.y = pkrtz(pv[10],pv[11]); *(uint2*)(pb + 1024 + c*16 + hi*8) = u; \
    u.x = pkrtz(pv[12],pv[13]); u.y = pkrtz(pv[14],pv[15]); *(uint2*)(pb + 1024 + (c+32)*16 + hi*8) = u; } \
  WAITLGKM0; \
  __builtin_amdgcn_s_barrier(); \
  MEMFENCE; \
  _Pragma("unroll") for (int s2=0;s2<2;++s2){ \
    _Pragma("unroll") for (int k2=0;k2<2;++k2){ \
      const uint4 afr = *(const uint4*)(PB + p*4096 + s2*2048 + k2*1024 + l*16); \
      const int gix = s2*4 + k2*2 + hi; \
      const int d0v = sub*64 + c; \
      const uint4 b0 = *(const uint4*)(VB + ((RR)&3)*16384 + d0v*128 + ((gix*16) ^ ((d0v&7)<<4))); \
      ctx0 = MFMA32(as_f16x8(afr), as_f16x8(b0), ctx0); \
      const int d1v = sub*64 + 32 + c; \
      const uint4 b1 = *(const uint4*)(VB + ((RR)&3)*16384 + d1v*128 + ((gix*16) ^ ((d1v&7)<<4))); \
      ctx1 = MFMA32(as_f16x8(afr), as_f16x8(b1), ctx1); } } \
  /* coalesced cached P f32 writer from PB: 4 lanes -> one 64B line */ \
  _Pragma("unroll") for (int o = 0; o < 4; ++o) { \
    const uint2 u = *(const uint2*)(pbr + (o>>1)*2048 + (o&1)*1024); \
    float4 f; \
    f.x = h2f((unsigned short)(u.x & 0xFFFFu)); \
    f.y = h2f((unsigned short)(u.x >> 16)); \
    f.z = h2f((unsigned short)(u.y & 0xFFFFu)); \
    f.w = h2f((unsigned short)(u.y >> 16)); \
    *(float4*)(Pdst + (size_t)(RR)*64 + o*16 + pqt*4) = f; \
  } \
  bcur = bn1; bn1 = bn2; \
} while(0)

// ---------- main: 1 WG/CU = (batch, 128 q-rows), 8 waves, two passes ----------
__global__ __launch_bounds__(512) void attn_main(
    const float* __restrict__ Q, const unsigned int* __restrict__ BM,
    const unsigned char* __restrict__ KIMG, const unsigned char* __restrict__ VIMG,
    float* __restrict__ ctxout, float* __restrict__ pout)
{
  extern __shared__ char lds[];
  char* KB = lds + OFF_KB;
  char* VB = lds + OFF_VB;
  char* PB = lds + OFF_PB;
  float* RED = (float*)(lds + OFF_RED);

  const int tid = threadIdx.x;
  const int w = tid >> 6, l = tid & 63;
  const int c = l & 31, hi = l >> 5;
  const int p = w >> 1, sub = w & 1;

  const int bid = blockIdx.x;
  const int xcd = bid & 7, jj = bid >> 3;
  const int b = xcd*2 + (jj >> 4);
  const int q0 = (jj & 15) * 128;
  const int qrow = q0 + p*32 + c;

  // Q fragments (fp16)
  uint4 qf[8];
  const float* qp0 = Q + ((size_t)b*LL + qrow)*DD;
#pragma unroll
  for (int s = 0; s < 8; ++s) {
    const float4 f0 = *(const float4*)(qp0 + s*16 + hi*8);
    const float4 f1 = *(const float4*)(qp0 + s*16 + hi*8 + 4);
    uint4 qv;
    qv.x = pkf16(f0.x, f0.y); qv.y = pkf16(f0.z, f0.w);
    qv.z = pkf16(f1.x, f1.y); qv.w = pkf16(f1.z, f1.w);
    qf[s] = qv;
  }

  const size_t imgb = ((size_t)b * NT) * 16384;
  const int soff = w*2048 + l*16;
  const unsigned int* BMl = BM + ((size_t)b*LL + qrow)*64 + sub;
  const int krow = sub*32 + c;
  const int kswz = (c & 15) << 4;

  // P-writer geometry: thread = (row = tid>>2, qt = tid&3)
  const int prow_r = tid >> 2;
  const int pqt = tid & 3;
  const int pp = prow_r >> 5, pc = prow_r & 31;
  const char* pbr = PB + pp*4096 + pc*16 + (pqt&1)*8 + (pqt>>1)*512;
  float* Pdst = pout + ((size_t)b*LL + q0 + prow_r)*LL;

  // ---------------- PASS 1: row sums of exp(S - CEXP) ----------------
  stage2(KIMG + imgb + 0*16384, KB + 0*16384, soff); SB0;
  unsigned bcur = BMl[0]; SB0;
  stage2(KIMG + imgb + 1*16384, KB + 1*16384, soff); SB0;
  unsigned bn1 = BMl[2]; SB0;
  stage2(KIMG + imgb + 2*16384, KB + 2*16384, soff); SB0;

  float psum[4] = {0.f, 0.f, 0.f, 0.f};
#pragma unroll 1
  for (int r = 0; r < 32; ++r) {
    P1BODY(r);
  }
  float sum = (psum[0] + psum[1]) + (psum[2] + psum[3]);
  sum += __shfl_xor(sum, 32);
  __syncthreads();                       // drains tail dummy stages too
  if (l < 32) RED[(p*2+sub)*32 + c] = sum;
  __syncthreads();
  float tot = RED[(p*2+sub)*32 + c] + RED[(p*2+(1-sub))*32 + c];
  tot = fmaxf(tot, 1e-35f);
  const float inv = 1.0f / tot;
  __syncthreads();

  // ---------------- PASS 2: P = exp(S-CEXP)*inv, write P (coalesced), ctx = P*V ----------------
  stage2(KIMG + imgb + 0*16384, KB + 0*16384, soff);
  stage2(VIMG + imgb + 0*16384, VB + 0*16384, soff); SB0;
  bcur = BMl[0]; SB0;
  stage2(KIMG + imgb + 1*16384, KB + 1*16384, soff);
  stage2(VIMG + imgb + 1*16384, VB + 1*16384, soff); SB0;
  bn1 = BMl[2]; SB0;
  stage2(KIMG + imgb + 2*16384, KB + 2*16384, soff);
  stage2(VIMG + imgb + 2*16384, VB + 2*16384, soff); SB0;

  f32x16 ctx0, ctx1;
#pragma unroll
  for (int i = 0; i < 16; ++i) { ctx0[i] = 0.f; ctx1[i] = 0.f; }

  P2BODY(0, 10);
  P2BODY(1, 14);
  P2BODY(2, 18);
#pragma unroll 1
  for (int r = 3; r < 32; ++r) {
    P2BODY(r, 22);
  }

  // ---- ctx epilogue
#pragma unroll
  for (int reg = 0; reg < 16; ++reg) {
    const int q = q0 + p*32 + (reg&3) + 8*(reg>>2) + 4*hi;
    float* cr = ctxout + ((size_t)b*LL + q)*DD;
    cr[sub*64 + c]      = ctx0[reg];
    cr[sub*64 + 32 + c] = ctx1[reg];
  }
}

// ---------- fallback (ws too small): simple correct version ----------
__global__ __launch_bounds__(256) void attn_naive(
    const float* __restrict__ Q, const float* __restrict__ K,
    const float* __restrict__ V, const int* __restrict__ M,
    float* __restrict__ ctx, float* __restrict__ pout)
{
  const int b = blockIdx.x >> 11;
  const int q = blockIdx.x & (LL-1);
  __shared__ float s[LL];
  __shared__ float red[256];
  const int tid = threadIdx.x;
  const float* qp = Q + ((size_t)b*LL + q)*DD;
  for (int kk = tid; kk < LL; kk += 256) {
    const float* kp = K + ((size_t)b*LL + kk)*DD;
    float a = 0.f;
    for (int d = 0; d < DD; ++d) a += qp[d]*kp[d];
    s[kk] = M[((size_t)b*LL + q)*LL + kk] ? a*SCALE : -1e9f;
  }
  __syncthreads();
  float mx = -3e38f;
  for (int kk = tid; kk < LL; kk += 256) mx = fmaxf(mx, s[kk]);
  red[tid] = mx; __syncthreads();
  for (int o = 128; o >= 1; o >>= 1) {
    if (tid < o) red[tid] = fmaxf(red[tid], red[tid+o]);
    __syncthreads();
  }
  const float mrow = red[0]; __syncthreads();
  float sm = 0.f;
  for (int kk = tid; kk < LL; kk += 256) { float e = __expf(s[kk]-mrow); s[kk] = e; sm += e; }
  red[tid] = sm; __syncthreads();
  for (int o = 128; o >= 1; o >>= 1) {
    if (tid < o) red[tid] += red[tid+o];
    __syncthreads();
  }
  const float inv = 1.0f / red[0]; __syncthreads();
  float* prow = pout + ((size_t)b*LL + q)*LL;
  for (int kk = tid; kk < LL; kk += 256) { s[kk] *= inv; prow[kk] = s[kk]; }
  __syncthreads();
  if (tid < DD) {
    float a = 0.f;
    for (int kk = 0; kk < LL; ++kk) a += s[kk]*V[((size_t)b*LL + kk)*DD + tid];
    ctx[((size_t)b*LL + q)*DD + tid] = a;
  }
}

extern "C" void kernel_launch(void* const* d_in, const int* in_sizes, int n_in,
                              void* d_out, int out_size, void* d_ws, size_t ws_size,
                              hipStream_t stream) {
  (void)in_sizes; (void)n_in; (void)out_size;
  const float* Q = (const float*)d_in[0];
  const float* K = (const float*)d_in[1];
  const float* V = (const float*)d_in[2];
  const int*   M = (const int*)d_in[3];
  float* ctx  = (float*)d_out;
  float* pout = ctx + (size_t)BB*LL*DD;
  const size_t IMG = (size_t)BB*NT*16384;        // 8 MB per image
  const size_t NBM = (size_t)BB*LL*(LL/32);      // 2.1M words = 8 MB
  const size_t WS_NEED = IMG*2 + NBM*4;
  if (ws_size >= WS_NEED) {
    unsigned char* kimg = (unsigned char*)d_ws;
    unsigned char* vimg = kimg + IMG;
    unsigned int*  bmw  = (unsigned int*)(vimg + IMG);
    hipFuncSetAttribute(reinterpret_cast<const void*>(attn_main),
                        hipFuncAttributeMaxDynamicSharedMemorySize, LDS_MAIN);
    prep_all<<<12288, 256, 0, stream>>>(K, V, M, kimg, vimg, bmw);
    attn_main<<<256, 512, LDS_MAIN, stream>>>(Q, bmw, kimg, vimg, ctx, pout);
  } else {
    attn_naive<<<BB*LL, 256, 0, stream>>>(Q, K, V, M, ctx, pout);
  }
}